// Round 23
// baseline (208.031 us; speedup 1.0000x reference)
//
#include <hip/hip_runtime.h>
#include <hip/hip_fp16.h>

static constexpr int Wd  = 128;
static constexpr int Hd  = 128;
static constexpr int HWc = Wd * Hd;    // 16384
static constexpr int Cc  = 128;
static constexpr int NHc = 4;
static constexpr int Bc  = 2;

__device__ __forceinline__ int refl(int i, int L) {
    i = i < 0 ? -i : i;
    return i >= L ? 2 * (L - 1) - i : i;
}

// float -> sortable u32 (strictly increasing bijection), and inverse
__device__ __forceinline__ unsigned f2s(float f) {
    unsigned u = __float_as_uint(f);
    return u ^ (0x80000000u | (unsigned)((int)u >> 31));
}
__device__ __forceinline__ float s2f(unsigned s) {
    unsigned u = (s & 0x80000000u) ? (s ^ 0x80000000u) : ~s;
    return __uint_as_float(u);
}

// float -> bf16 bits (round-to-nearest-even), as low 16 of a u32
__device__ __forceinline__ unsigned f2bf(float f) {
    unsigned u = __float_as_uint(f);
    u += 0x7fffu + ((u >> 16) & 1u);
    return u >> 16;
}

// ---------------- Kernel A: fused depthwise 3x3 (q,k,v) + bias + relu ----------------
__global__ __launch_bounds__(256) void dw3_kernel(
    const float* __restrict__ vid,
    const float* __restrict__ wq, const float* __restrict__ bq,
    const float* __restrict__ wk, const float* __restrict__ bk,
    const float* __restrict__ wv, const float* __restrict__ bv,
    float* __restrict__ yq, float* __restrict__ yk, float* __restrict__ yv)
{
    int pix = blockIdx.x * 256 + threadIdx.x;
    int bc  = blockIdx.y;            // b*C + c
    int c   = bc & (Cc - 1);
    int y = pix >> 7, x = pix & (Wd - 1);
    const float* src = vid + bc * HWc;
    const float* wpq = wq + c * 9;
    const float* wpk = wk + c * 9;
    const float* wpv = wv + c * 9;
    float aq = 0.f, ak = 0.f, av = 0.f;
    #pragma unroll
    for (int ky = 0; ky < 3; ++ky) {
        int iy = y + ky - 1;
        if (iy < 0 || iy >= Hd) continue;
        #pragma unroll
        for (int kx = 0; kx < 3; ++kx) {
            int ix = x + kx - 1;
            if (ix < 0 || ix >= Wd) continue;
            float v = src[iy * Wd + ix];
            int k = ky * 3 + kx;
            aq = fmaf(v, wpq[k], aq);
            ak = fmaf(v, wpk[k], ak);
            av = fmaf(v, wpv[k], av);
        }
    }
    int o = bc * HWc + pix;
    yq[o] = fmaxf(aq + bq[c], 0.f);
    yk[o] = fmaxf(ak + bk[c], 0.f);
    yv[o] = fmaxf(av + bv[c], 0.f);
}

// ---------------- Kernel B/D: pointwise GEMM, 128o x 64p tile -------------------------
__global__ __launch_bounds__(256) void pw_kernel(
    const float* y0p, const float* y1p, const float* y2p,
    const float* __restrict__ w0,  const float* __restrict__ w1,  const float* __restrict__ w2,
    const float* __restrict__ b0,  const float* __restrict__ b1,  const float* __restrict__ b2,
    float* o0, float* o1, float* o2,
    float scale0)
{
    extern __shared__ float lds[];
    float* wl = lds;            // [64 cc][132]  (o-transposed weights)
    float* yl = lds + 8448;     // [64 cc][68]   (64 pixels + pad)

    int z = blockIdx.z;
    const float* yin  = z == 0 ? y0p : (z == 1 ? y1p : y2p);
    const float* wmat = z == 0 ? w0  : (z == 1 ? w1  : w2);
    const float* bias = z == 0 ? b0  : (z == 1 ? b1  : b2);
    float* out        = z == 0 ? o0  : (z == 1 ? o1  : o2);
    float scale       = z == 0 ? scale0 : 1.f;

    int tid = threadIdx.x;
    int ot = tid & 15, pt = tid >> 4;
    int gp  = blockIdx.x * 64;
    int b   = gp >> 14;
    int pof = gp & (HWc - 1);
    const float* yb = yin + b * Cc * HWc + pof;

    float acc[2][4][4];            // [oh][oi][pi]
    #pragma unroll
    for (int a = 0; a < 2; ++a)
        #pragma unroll
        for (int i = 0; i < 4; ++i)
            #pragma unroll
            for (int j = 0; j < 4; ++j) acc[a][i][j] = 0.f;

    for (int kh = 0; kh < 2; ++kh) {
        int c0 = kh * 64;
        for (int i = tid; i < 8192; i += 256) {
            int cc = i & 63, o = i >> 6;
            wl[cc * 132 + o] = wmat[o * 128 + c0 + cc];
        }
        for (int i = tid; i < 4096; i += 256) {
            int p = i & 63, cc = i >> 6;
            yl[cc * 68 + p] = yb[(c0 + cc) * HWc + p];
        }
        __syncthreads();
        #pragma unroll 4
        for (int cc = 0; cc < 64; ++cc) {
            float4 wv[2];
            wv[0] = *(const float4*)(wl + cc * 132 + 4 * ot);
            wv[1] = *(const float4*)(wl + cc * 132 + 64 + 4 * ot);
            const float4 pv = *(const float4*)(yl + cc * 68 + 4 * pt);
            const float pp[4] = {pv.x, pv.y, pv.z, pv.w};
            #pragma unroll
            for (int oh = 0; oh < 2; ++oh) {
                const float wo[4] = {wv[oh].x, wv[oh].y, wv[oh].z, wv[oh].w};
                #pragma unroll
                for (int oi = 0; oi < 4; ++oi)
                    #pragma unroll
                    for (int pi = 0; pi < 4; ++pi)
                        acc[oh][oi][pi] = fmaf(wo[oi], pp[pi], acc[oh][oi][pi]);
            }
        }
        __syncthreads();
    }

    float* ob = out + b * Cc * HWc + pof;
    #pragma unroll
    for (int oh = 0; oh < 2; ++oh)
        #pragma unroll
        for (int oi = 0; oi < 4; ++oi) {
            int o = oh * 64 + 4 * ot + oi;
            float bo = bias[o];
            float4 v;
            v.x = (acc[oh][oi][0] + bo) * scale;
            v.y = (acc[oh][oi][1] + bo) * scale;
            v.z = (acc[oh][oi][2] + bo) * scale;
            v.w = (acc[oh][oi][3] + bo) * scale;
            *(float4*)(ob + o * HWc + 4 * pt) = v;
        }
}

// ---------------- Kernel C: fused neighborhood attention, 16 lanes/pixel --------------
// Round-23 structural change: rounds 17-22 proved occupancy pinned ~41% / attn ~110us
// against every static-resource lever (LDS 39-67KB, VGPR 52, launch-bounds arg2) ->
// the bound is per-thread serial chain length. Split each pixel across 16 lanes
// (1024-thread block, 16 waves): lane ll owns 4 offsets (half-row) for QK/rank and 2
// channels for PV. Per-thread VALU ~1600 -> ~1000; waves/block 8 -> 16; LDS unchanged
// 52.4 KB -> 2 blocks/CU = 32 waves = 100% ceiling.
// Tie semantics exact: in-lane indices consecutive; partner ll^m lower-gidx iff ll has
// msb(m) set. Single barrier; ent scatter wave-internal (16 producer lanes == 16
// consumer lanes of the pixel, same wave). bf16 V (linear path, error << budget).
// XCD-head affinity bn=bid&7 (FETCH 123->24.7 MB, round 16).
__global__ __launch_bounds__(1024) void attn_kernel(
    const float* q, const float* __restrict__ kk,
    const float* __restrict__ vv, float* att)
{
    extern __shared__ float alds[];
    float* kreg       = alds;                        // [8][225][4] K SoA, fp32
    unsigned* vreg    = (unsigned*)(alds + 7200);    // [8][225][2] V SoA, bf16 pairs
    float* q_l        = alds + 7200 + 3600;          // [64][36]; ent aliases per-pixel
    int tid = threadIdx.x;
    int bid = blockIdx.x;
    int bn = bid & 7;                      // head-on-XCD affinity
    int t  = bid >> 3;                     // 0..255
    int x0 = (t & 15) * 8, y0 = (t >> 4) * 8;
    const float* kb = kk + bn * 32 * HWc;
    const float* vb = vv + bn * 32 * HWc;

    int ll = tid & 15;             // lane-in-pixel: offsets ll*4..ll*4+3 / channels 2ll,2ll+1
    int pl = tid >> 4;             // pixel 0..63
    int px = pl & 7, py = pl >> 3;
    int gq = (y0 + py) * Wd + (x0 + px);

    // ========== stage K (fp32) + V (bf16 pairs) + q, one burst ======================
    {
        int cb = tid & 7;
        const float* kc = kb + cb * 4 * HWc;
        const float* vc = vb + cb * 4 * HWc;
        float* kq    = kreg + cb * 900;
        unsigned* vq = vreg + cb * 450;
        for (int u = tid; u < 1800; u += 1024) {
            int pix = u >> 3;
            int ry = pix / 15, rx = pix - ry * 15;
            int go = refl(y0 - 4 + ry, Hd) * Wd + refl(x0 - 4 + rx, Wd);
            float4 a, b;
            a.x = kc[go];
            a.y = kc[HWc + go];
            a.z = kc[2 * HWc + go];
            a.w = kc[3 * HWc + go];
            b.x = vc[go];
            b.y = vc[HWc + go];
            b.z = vc[2 * HWc + go];
            b.w = vc[3 * HWc + go];
            *(float4*)(kq + pix * 4) = a;
            uint2 pk;
            pk.x = f2bf(b.x) | (f2bf(b.y) << 16);
            pk.y = f2bf(b.z) | (f2bf(b.w) << 16);
            *(uint2*)(vq + pix * 2) = pk;
        }
        const float* qb = q + bn * 32 * HWc;
        for (int u = tid; u < 2048; u += 1024) {
            int c = u >> 6, pix = u & 63;
            q_l[pix * 36 + c] = qb[c * HWc + (y0 + (pix >> 3)) * Wd + x0 + (pix & 7)];
        }
    }
    __syncthreads();   // the ONLY barrier

    // ========== QK: my 4 offsets (half-row) x all 32 channels =======================
    float d[4];
    #pragma unroll
    for (int i = 0; i < 4; ++i) d[i] = 0.f;
    {
        int base_p = (py + (ll >> 1)) * 15 + px + (ll & 1) * 4;
        const float* myq = q_l + pl * 36;
        #pragma unroll
        for (int cq = 0; cq < 8; ++cq) {
            const float4 q4 = *(const float4*)(myq + cq * 4);
            const float* rq = kreg + cq * 900 + base_p * 4;
            #pragma unroll
            for (int j = 0; j < 4; ++j) {
                const float4 kv = *(const float4*)(rq + j * 4);
                d[j] = fmaf(q4.x, kv.x, fmaf(q4.y, kv.y, fmaf(q4.z, kv.z, fmaf(q4.w, kv.w, d[j]))));
            }
        }
    }
    unsigned s[4];
    #pragma unroll
    for (int i = 0; i < 4; ++i) s[i] = f2s(d[i]);

    // ========== cooperative top-16 ranking (byte counters, 16-lane) =================
    unsigned rkc[4];
    #pragma unroll
    for (int i = 0; i < 4; ++i) rkc[i] = 0u;
    #pragma unroll
    for (int i = 0; i < 3; ++i) {
        #pragma unroll
        for (int j = i + 1; j < 4; ++j) {
            rkc[i] += (unsigned)(s[j] > s[i]);   // j (higher idx) beats i on strict >
            rkc[j] += (unsigned)(s[i] >= s[j]);  // i (lower idx) beats j on >=
        }
    }
    #pragma unroll
    for (int m = 1; m <= 15; ++m) {
        // partner ll^m has lower global indices iff ll's msb(m) bit is set
        unsigned plow = ((m >= 8) ? (ll >> 3) : (m >= 4) ? (ll >> 2)
                       : (m >= 2) ? (ll >> 1) : ll) & 1;
        #pragma unroll
        for (int j = 0; j < 4; ++j) {
            unsigned spa = __shfl_xor(s[j], m) + plow;   // beat <=> spa > s_i
            #pragma unroll
            for (int i = 0; i < 4; ++i)
                rkc[i] += (unsigned)(spa > s[i]);
        }
    }

    // ========== softmax over the selected 16 (16-lane butterfly) ====================
    unsigned smax = s[0];
    #pragma unroll
    for (int i = 1; i < 4; ++i) smax = max(smax, s[i]);
    smax = max(smax, (unsigned)__shfl_xor(smax, 1));
    smax = max(smax, (unsigned)__shfl_xor(smax, 2));
    smax = max(smax, (unsigned)__shfl_xor(smax, 4));
    smax = max(smax, (unsigned)__shfl_xor(smax, 8));
    float dmax = s2f(smax);
    float w[4];
    float sum = 0.f;
    #pragma unroll
    for (int i = 0; i < 4; ++i) {
        float e = (rkc[i] < 16u) ? __expf(s2f(s[i]) - dmax) : 0.f;
        w[i] = e;
        sum += e;
    }
    sum += __shfl_xor(sum, 1);
    sum += __shfl_xor(sum, 2);
    sum += __shfl_xor(sum, 4);
    sum += __shfl_xor(sum, 8);
    float inv = 1.0f / sum;

    // ---- scatter selected entries into the pixel's own q slot (wave-internal:
    //      producers == consumers == the 16 lanes of this pixel group)
    unsigned* entp = (unsigned*)(q_l + pl * 36);
    #pragma unroll
    for (int i = 0; i < 4; ++i) {
        if (rkc[i] < 16u) {
            unsigned hb = __half_as_ushort(__float2half(w[i]));
            entp[rkc[i]] = (hb << 16) | (unsigned)(ll * 4 + i);
        }
    }

    // ========== PV: my channel pair (2ll, 2ll+1) over the 16 selected offsets =======
    uint4 ea = *(const uint4*)(entp);
    uint4 eb = *(const uint4*)(entp + 4);
    uint4 ec = *(const uint4*)(entp + 8);
    uint4 ed = *(const uint4*)(entp + 12);
    unsigned ent[16] = {ea.x, ea.y, ea.z, ea.w, eb.x, eb.y, eb.z, eb.w,
                        ec.x, ec.y, ec.z, ec.w, ed.x, ed.y, ed.z, ed.w};
    float a0 = 0.f, a1 = 0.f;
    int pbase = py * 15 + px;
    const unsigned* rq = vreg + (ll >> 1) * 450 + (ll & 1);
    #pragma unroll
    for (int e = 0; e < 16; ++e) {
        unsigned en = ent[e];
        int tt = en & 63;
        int dy = tt >> 3, dx = tt & 7;
        float wg = __half2float(__ushort_as_half((unsigned short)(en >> 16)));
        unsigned pv = rq[(pbase + dy * 15 + dx) * 2];
        float v0 = __uint_as_float(pv << 16);
        float v1 = __uint_as_float(pv & 0xffff0000u);
        a0 = fmaf(wg, v0, a0);
        a1 = fmaf(wg, v1, a1);
    }

    float* op = att + (bn * 32 + 2 * ll) * HWc + gq;
    op[0]   = a0 * inv;
    op[HWc] = a1 * inv;
}

// ---------------------------------- launcher ------------------------------------------
extern "C" void kernel_launch(void* const* d_in, const int* in_sizes, int n_in,
                              void* d_out, int out_size, void* d_ws, size_t ws_size,
                              hipStream_t stream)
{
    const float* vid  = (const float*)d_in[0];
    const float* qdww = (const float*)d_in[1];
    const float* qdwb = (const float*)d_in[2];
    const float* qpww = (const float*)d_in[3];
    const float* qpwb = (const float*)d_in[4];
    const float* kdww = (const float*)d_in[5];
    const float* kdwb = (const float*)d_in[6];
    const float* kpww = (const float*)d_in[7];
    const float* kpwb = (const float*)d_in[8];
    const float* vdww = (const float*)d_in[9];
    const float* vdwb = (const float*)d_in[10];
    const float* vpww = (const float*)d_in[11];
    const float* vpwb = (const float*)d_in[12];
    const float* pjw  = (const float*)d_in[13];
    const float* pjb  = (const float*)d_in[14];

    float* ws = (float*)d_ws;
    const size_t SZ = (size_t)Bc * Cc * HWc;   // 16 MB each; total ws use 48 MB
    float* buf0 = ws;            // q-dw -> q -> att (in-place, own-tile accesses only)
    float* buf1 = ws + SZ;       // k-dw -> k
    float* buf2 = ws + 2 * SZ;   // v-dw -> v

    hipFuncSetAttribute((const void*)pw_kernel,   hipFuncAttributeMaxDynamicSharedMemorySize, 51200);
    hipFuncSetAttribute((const void*)attn_kernel, hipFuncAttributeMaxDynamicSharedMemorySize, 52416);

    dw3_kernel<<<dim3(HWc / 256, Bc * Cc), 256, 0, stream>>>(
        vid, qdww, qdwb, kdww, kdwb, vdww, vdwb, buf0, buf1, buf2);

    const float scale = 0.17677669529663687f;
    pw_kernel<<<dim3((Bc * HWc) / 64, 1, 3), 256, 51200, stream>>>(
        buf0, buf1, buf2, qpww, kpww, vpww, qpwb, kpwb, vpwb, buf0, buf1, buf2, scale);

    attn_kernel<<<dim3(2048, 1, 1), 1024, 52416, stream>>>(
        buf0, buf1, buf2, buf0);

    pw_kernel<<<dim3((Bc * HWc) / 64, 1, 1), 256, 51200, stream>>>(
        buf0, buf0, buf0, pjw, pjw, pjw, pjb, pjb, pjb, (float*)d_out, (float*)d_out, (float*)d_out, 1.f);
}

// Round 24
// 176.795 us; speedup vs baseline: 1.1767x; 1.1767x over previous
//
#include <hip/hip_runtime.h>
#include <hip/hip_fp16.h>

static constexpr int Wd  = 128;
static constexpr int Hd  = 128;
static constexpr int HWc = Wd * Hd;    // 16384
static constexpr int Cc  = 128;
static constexpr int NHc = 4;
static constexpr int Bc  = 2;

__device__ __forceinline__ int refl(int i, int L) {
    i = i < 0 ? -i : i;
    return i >= L ? 2 * (L - 1) - i : i;
}

// float -> sortable u32 (strictly increasing bijection), and inverse
__device__ __forceinline__ unsigned f2s(float f) {
    unsigned u = __float_as_uint(f);
    return u ^ (0x80000000u | (unsigned)((int)u >> 31));
}
__device__ __forceinline__ float s2f(unsigned s) {
    unsigned u = (s & 0x80000000u) ? (s ^ 0x80000000u) : ~s;
    return __uint_as_float(u);
}

// float -> bf16 bits (round-to-nearest-even), as low 16 of a u32
__device__ __forceinline__ unsigned f2bf(float f) {
    unsigned u = __float_as_uint(f);
    u += 0x7fffu + ((u >> 16) & 1u);
    return u >> 16;
}

// Round-24: whole-chain pixel-band XCD affinity. Image = 8 bands of 2048 pixels;
// every kernel remaps its 1-D block id so (linear_id % 8) == band of the pixels it
// touches -> dw-write, pw-read/write, attn k/v/q-read, proj-read all land in the SAME
// per-XCD L2 (mechanism proven in round 16: attn FETCH 123->24.7 MB). Pure index
// permutation; no correctness impact.

// ---------------- Kernel A: fused depthwise 3x3 (q,k,v) + bias + relu ----------------
__global__ __launch_bounds__(256) void dw3_kernel(
    const float* __restrict__ vid,
    const float* __restrict__ wq, const float* __restrict__ bq,
    const float* __restrict__ wk, const float* __restrict__ bk,
    const float* __restrict__ wv, const float* __restrict__ bv,
    float* __restrict__ yq, float* __restrict__ yk, float* __restrict__ yv)
{
    int bid = blockIdx.x;
    int bxd = bid & 63;              // 64 pixel-blocks of 256
    int bc  = bid >> 6;              // b*C + c
    int bx  = ((bxd & 7) << 3) | (bxd >> 3);   // band(bx>>3) == bid%8
    int pix = bx * 256 + threadIdx.x;
    int c   = bc & (Cc - 1);
    int y = pix >> 7, x = pix & (Wd - 1);
    const float* src = vid + bc * HWc;
    const float* wpq = wq + c * 9;
    const float* wpk = wk + c * 9;
    const float* wpv = wv + c * 9;
    float aq = 0.f, ak = 0.f, av = 0.f;
    #pragma unroll
    for (int ky = 0; ky < 3; ++ky) {
        int iy = y + ky - 1;
        if (iy < 0 || iy >= Hd) continue;
        #pragma unroll
        for (int kx = 0; kx < 3; ++kx) {
            int ix = x + kx - 1;
            if (ix < 0 || ix >= Wd) continue;
            float v = src[iy * Wd + ix];
            int k = ky * 3 + kx;
            aq = fmaf(v, wpq[k], aq);
            ak = fmaf(v, wpk[k], ak);
            av = fmaf(v, wpv[k], av);
        }
    }
    int o = bc * HWc + pix;
    yq[o] = fmaxf(aq + bq[c], 0.f);
    yk[o] = fmaxf(ak + bk[c], 0.f);
    yv[o] = fmaxf(av + bv[c], 0.f);
}

// ---------------- Kernel B/D: pointwise GEMM, 128o x 64p tile, band-affine ------------
// 1-D grid; bid>>9 selects conv (0..2 for qkv, always 0 for proj), low 9 bits remapped
// so (bid%8) == pixel band ((bx>>5)&7). In-place safe (p-split; own column only).
__global__ __launch_bounds__(256) void pw_kernel(
    const float* y0p, const float* y1p, const float* y2p,
    const float* __restrict__ w0,  const float* __restrict__ w1,  const float* __restrict__ w2,
    const float* __restrict__ b0,  const float* __restrict__ b1,  const float* __restrict__ b2,
    float* o0, float* o1, float* o2,
    float scale0)
{
    extern __shared__ float lds[];
    float* wl = lds;            // [64 cc][132]  (o-transposed weights)
    float* yl = lds + 8448;     // [64 cc][68]   (64 pixels + pad)

    int bidl = blockIdx.x;
    int z    = bidl >> 9;
    int bxd  = bidl & 511;
    int bx   = (bxd & 256) | ((bxd & 7) << 5) | ((bxd >> 3) & 31);  // band == bid%8
    const float* yin  = z == 0 ? y0p : (z == 1 ? y1p : y2p);
    const float* wmat = z == 0 ? w0  : (z == 1 ? w1  : w2);
    const float* bias = z == 0 ? b0  : (z == 1 ? b1  : b2);
    float* out        = z == 0 ? o0  : (z == 1 ? o1  : o2);
    float scale       = z == 0 ? scale0 : 1.f;

    int tid = threadIdx.x;
    int ot = tid & 15, pt = tid >> 4;
    int gp  = bx * 64;
    int b   = gp >> 14;
    int pof = gp & (HWc - 1);
    const float* yb = yin + b * Cc * HWc + pof;

    float acc[2][4][4];            // [oh][oi][pi]
    #pragma unroll
    for (int a = 0; a < 2; ++a)
        #pragma unroll
        for (int i = 0; i < 4; ++i)
            #pragma unroll
            for (int j = 0; j < 4; ++j) acc[a][i][j] = 0.f;

    for (int kh = 0; kh < 2; ++kh) {
        int c0 = kh * 64;
        for (int i = tid; i < 8192; i += 256) {
            int cc = i & 63, o = i >> 6;
            wl[cc * 132 + o] = wmat[o * 128 + c0 + cc];
        }
        for (int i = tid; i < 4096; i += 256) {
            int p = i & 63, cc = i >> 6;
            yl[cc * 68 + p] = yb[(c0 + cc) * HWc + p];
        }
        __syncthreads();
        #pragma unroll 4
        for (int cc = 0; cc < 64; ++cc) {
            float4 wv[2];
            wv[0] = *(const float4*)(wl + cc * 132 + 4 * ot);
            wv[1] = *(const float4*)(wl + cc * 132 + 64 + 4 * ot);
            const float4 pv = *(const float4*)(yl + cc * 68 + 4 * pt);
            const float pp[4] = {pv.x, pv.y, pv.z, pv.w};
            #pragma unroll
            for (int oh = 0; oh < 2; ++oh) {
                const float wo[4] = {wv[oh].x, wv[oh].y, wv[oh].z, wv[oh].w};
                #pragma unroll
                for (int oi = 0; oi < 4; ++oi)
                    #pragma unroll
                    for (int pi = 0; pi < 4; ++pi)
                        acc[oh][oi][pi] = fmaf(wo[oi], pp[pi], acc[oh][oi][pi]);
            }
        }
        __syncthreads();
    }

    float* ob = out + b * Cc * HWc + pof;
    #pragma unroll
    for (int oh = 0; oh < 2; ++oh)
        #pragma unroll
        for (int oi = 0; oi < 4; ++oi) {
            int o = oh * 64 + 4 * ot + oi;
            float bo = bias[o];
            float4 v;
            v.x = (acc[oh][oi][0] + bo) * scale;
            v.y = (acc[oh][oi][1] + bo) * scale;
            v.z = (acc[oh][oi][2] + bo) * scale;
            v.w = (acc[oh][oi][3] + bo) * scale;
            *(float4*)(ob + o * HWc + 4 * pt) = v;
        }
}

// ---------------- Kernel C: fused neighborhood attention, band-affine -----------------
// Round-21 body (512 threads, 8 lanes/pixel, bf16 V, single barrier) -- round-23's
// 16-lane variant regressed (1024-block barrier/granularity cost > chain savings).
// Round-24 bid decode: (bid&7) == pixel band (y0>>4); remaining 8 bits = ty-lsb, tx,
// bn. Same-band blocks (all heads) share one XCD whose L2 holds that band's k+v+q
// (~4 MB) -- replaces round-16 head affinity with producer-aligned pixel affinity.
__global__ __launch_bounds__(512) void attn_kernel(
    const float* q, const float* __restrict__ kk,
    const float* __restrict__ vv, float* att)
{
    extern __shared__ float alds[];
    float* kreg       = alds;                        // [8][225][4] K SoA, fp32
    unsigned* vreg    = (unsigned*)(alds + 7200);    // [8][225][2] V SoA, bf16 pairs
    float* q_l        = alds + 7200 + 3600;          // [64][36]; ent aliases per-pixel
    int tid = threadIdx.x;
    int bid = blockIdx.x;
    int band = bid & 7;
    int r    = bid >> 3;
    int ty = (band << 1) | (r & 1);
    int tx = (r >> 1) & 15;
    int bn = (r >> 5) & 7;
    int x0 = tx * 8, y0 = ty * 8;     // y0>>4 == band
    const float* kb = kk + bn * 32 * HWc;
    const float* vb = vv + bn * 32 * HWc;

    int qq = tid & 7;
    int pl = tid >> 3;             // pixel 0..63
    int px = pl & 7, py = pl >> 3;
    int gq = (y0 + py) * Wd + (x0 + px);

    // ========== stage K (fp32) + V (bf16 pairs) + q, one burst ======================
    {
        int cb = tid & 7;
        const float* kc = kb + cb * 4 * HWc;
        const float* vc = vb + cb * 4 * HWc;
        float* kq    = kreg + cb * 900;
        unsigned* vq = vreg + cb * 450;
        for (int u = tid; u < 1800; u += 512) {
            int pix = u >> 3;
            int ry = pix / 15, rx = pix - ry * 15;
            int go = refl(y0 - 4 + ry, Hd) * Wd + refl(x0 - 4 + rx, Wd);
            float4 a, b;
            a.x = kc[go];
            a.y = kc[HWc + go];
            a.z = kc[2 * HWc + go];
            a.w = kc[3 * HWc + go];
            b.x = vc[go];
            b.y = vc[HWc + go];
            b.z = vc[2 * HWc + go];
            b.w = vc[3 * HWc + go];
            *(float4*)(kq + pix * 4) = a;
            uint2 pk;
            pk.x = f2bf(b.x) | (f2bf(b.y) << 16);
            pk.y = f2bf(b.z) | (f2bf(b.w) << 16);
            *(uint2*)(vq + pix * 2) = pk;
        }
        const float* qb = q + bn * 32 * HWc;
        for (int u = tid; u < 2048; u += 512) {
            int c = u >> 6, pix = u & 63;
            q_l[pix * 36 + c] = qb[c * HWc + (y0 + (pix >> 3)) * Wd + x0 + (pix & 7)];
        }
    }
    __syncthreads();   // the ONLY barrier

    // ========== QK: my 8 offsets (row dy=qq) x all 32 channels ======================
    float d[8];
    #pragma unroll
    for (int i = 0; i < 8; ++i) d[i] = 0.f;
    {
        int base_p = (py + qq) * 15 + px;
        const float* myq = q_l + pl * 36;
        #pragma unroll
        for (int cq = 0; cq < 8; ++cq) {
            const float4 q4 = *(const float4*)(myq + cq * 4);
            const float* rq = kreg + cq * 900 + base_p * 4;
            #pragma unroll
            for (int j = 0; j < 8; ++j) {
                const float4 kv = *(const float4*)(rq + j * 4);
                d[j] = fmaf(q4.x, kv.x, fmaf(q4.y, kv.y, fmaf(q4.z, kv.z, fmaf(q4.w, kv.w, d[j]))));
            }
        }
    }
    unsigned s[8];
    #pragma unroll
    for (int i = 0; i < 8; ++i) s[i] = f2s(d[i]);

    // ========== cooperative top-16 ranking (byte counters) ==========================
    unsigned rkc[8];
    #pragma unroll
    for (int i = 0; i < 8; ++i) rkc[i] = 0u;
    #pragma unroll
    for (int i = 0; i < 7; ++i) {
        #pragma unroll
        for (int j = i + 1; j < 8; ++j) {
            rkc[i] += (unsigned)(s[j] > s[i]);   // j (higher idx) beats i on strict >
            rkc[j] += (unsigned)(s[i] >= s[j]);  // i (lower idx) beats j on >=
        }
    }
    #pragma unroll
    for (int m = 1; m <= 7; ++m) {
        unsigned plow = ((m >= 4) ? (qq >> 2) : (m >= 2) ? (qq >> 1) : qq) & 1;
        #pragma unroll
        for (int j = 0; j < 8; ++j) {
            unsigned spa = __shfl_xor(s[j], m) + plow;   // beat <=> spa > s_i
            #pragma unroll
            for (int i = 0; i < 8; ++i)
                rkc[i] += (unsigned)(spa > s[i]);
        }
    }

    // ========== softmax over the selected 16 (8-lane butterfly) =====================
    unsigned smax = s[0];
    #pragma unroll
    for (int i = 1; i < 8; ++i) smax = max(smax, s[i]);
    smax = max(smax, (unsigned)__shfl_xor(smax, 1));
    smax = max(smax, (unsigned)__shfl_xor(smax, 2));
    smax = max(smax, (unsigned)__shfl_xor(smax, 4));
    float dmax = s2f(smax);
    float w[8];
    float sum = 0.f;
    #pragma unroll
    for (int i = 0; i < 8; ++i) {
        float e = (rkc[i] < 16u) ? __expf(s2f(s[i]) - dmax) : 0.f;
        w[i] = e;
        sum += e;
    }
    sum += __shfl_xor(sum, 1);
    sum += __shfl_xor(sum, 2);
    sum += __shfl_xor(sum, 4);
    float inv = 1.0f / sum;

    // ---- scatter selected entries into the pixel's own q slot (wave-internal:
    //      producers == consumers == the 8 lanes of this pixel group)
    unsigned* entp = (unsigned*)(q_l + pl * 36);
    #pragma unroll
    for (int i = 0; i < 8; ++i) {
        if (rkc[i] < 16u) {
            unsigned hb = __half_as_ushort(__float2half(w[i]));
            entp[rkc[i]] = (hb << 16) | (unsigned)(qq * 8 + i);
        }
    }

    // ========== PV: my channel quad (qq) over the 16 selected offsets ===============
    uint4 ea = *(const uint4*)(entp);
    uint4 eb = *(const uint4*)(entp + 4);
    uint4 ec = *(const uint4*)(entp + 8);
    uint4 ed = *(const uint4*)(entp + 12);
    unsigned ent[16] = {ea.x, ea.y, ea.z, ea.w, eb.x, eb.y, eb.z, eb.w,
                        ec.x, ec.y, ec.z, ec.w, ed.x, ed.y, ed.z, ed.w};
    float a0 = 0.f, a1 = 0.f, a2 = 0.f, a3 = 0.f;
    int pbase = py * 15 + px;
    const unsigned* rq = vreg + qq * 450;
    #pragma unroll
    for (int e = 0; e < 16; ++e) {
        unsigned en = ent[e];
        int tt = en & 63;
        int dy = tt >> 3, dx = tt & 7;
        float wg = __half2float(__ushort_as_half((unsigned short)(en >> 16)));
        const uint2 pv = *(const uint2*)(rq + (pbase + dy * 15 + dx) * 2);
        float v0 = __uint_as_float(pv.x << 16);
        float v1 = __uint_as_float(pv.x & 0xffff0000u);
        float v2 = __uint_as_float(pv.y << 16);
        float v3 = __uint_as_float(pv.y & 0xffff0000u);
        a0 = fmaf(wg, v0, a0);
        a1 = fmaf(wg, v1, a1);
        a2 = fmaf(wg, v2, a2);
        a3 = fmaf(wg, v3, a3);
    }

    float* op = att + (bn * 32 + qq * 4) * HWc + gq;
    op[0]       = a0 * inv;
    op[HWc]     = a1 * inv;
    op[2 * HWc] = a2 * inv;
    op[3 * HWc] = a3 * inv;
}

// ---------------------------------- launcher ------------------------------------------
extern "C" void kernel_launch(void* const* d_in, const int* in_sizes, int n_in,
                              void* d_out, int out_size, void* d_ws, size_t ws_size,
                              hipStream_t stream)
{
    const float* vid  = (const float*)d_in[0];
    const float* qdww = (const float*)d_in[1];
    const float* qdwb = (const float*)d_in[2];
    const float* qpww = (const float*)d_in[3];
    const float* qpwb = (const float*)d_in[4];
    const float* kdww = (const float*)d_in[5];
    const float* kdwb = (const float*)d_in[6];
    const float* kpww = (const float*)d_in[7];
    const float* kpwb = (const float*)d_in[8];
    const float* vdww = (const float*)d_in[9];
    const float* vdwb = (const float*)d_in[10];
    const float* vpww = (const float*)d_in[11];
    const float* vpwb = (const float*)d_in[12];
    const float* pjw  = (const float*)d_in[13];
    const float* pjb  = (const float*)d_in[14];

    float* ws = (float*)d_ws;
    const size_t SZ = (size_t)Bc * Cc * HWc;   // 16 MB each; total ws use 48 MB
    float* buf0 = ws;            // q-dw -> q -> att (in-place, own-tile accesses only)
    float* buf1 = ws + SZ;       // k-dw -> k
    float* buf2 = ws + 2 * SZ;   // v-dw -> v

    hipFuncSetAttribute((const void*)pw_kernel,   hipFuncAttributeMaxDynamicSharedMemorySize, 51200);
    hipFuncSetAttribute((const void*)attn_kernel, hipFuncAttributeMaxDynamicSharedMemorySize, 52416);

    dw3_kernel<<<dim3(64 * Bc * Cc, 1, 1), 256, 0, stream>>>(
        vid, qdww, qdwb, kdww, kdwb, vdww, vdwb, buf0, buf1, buf2);

    const float scale = 0.17677669529663687f;
    pw_kernel<<<dim3(512 * 3, 1, 1), 256, 51200, stream>>>(
        buf0, buf1, buf2, qpww, kpww, vpww, qpwb, kpwb, vpwb, buf0, buf1, buf2, scale);

    attn_kernel<<<dim3(2048, 1, 1), 512, 52416, stream>>>(
        buf0, buf1, buf2, buf0);

    pw_kernel<<<dim3(512, 1, 1), 256, 51200, stream>>>(
        buf0, buf0, buf0, pjw, pjw, pjw, pjb, pjb, pjb, (float*)d_out, (float*)d_out, (float*)d_out, 1.f);
}